// Round 23
// baseline (600.734 us; speedup 1.0000x reference)
//
#include <hip/hip_runtime.h>
#include <math.h>

#define NP 256
#define HID 512
#define KB 8        // LU panel width

typedef short bf16x8 __attribute__((ext_vector_type(8)));
typedef float f32x4v __attribute__((ext_vector_type(4)));

// RNE bf16 with exact residual (v - bf16(v) is exactly representable).
__device__ __forceinline__ short bf16_rne(float v, float& rem) {
    unsigned u = __float_as_uint(v);
    unsigned r = (u + 0x7FFFu + ((u >> 16) & 1u)) & 0xFFFF0000u;
    rem = v - __uint_as_float(r);
    return (short)(r >> 16);
}
// 3-way RNE split: v = h + m + lo + r3, |r3| <= 2^-27 |v| (unbiased).
__device__ __forceinline__ void split3(float v, short& h, short& m, short& lo) {
    float r1, r2;
    h = bf16_rne(v, r1);
    m = bf16_rne(r1, r2);
    unsigned u2 = __float_as_uint(r2);
    lo = (short)((u2 + 0x7FFFu + ((u2 >> 16) & 1u)) >> 16);
}

// v6 MLP (r23): double-buffered pA pipeline. r18-r22 ran layer-0 (tanh +
// split3 VALU) between two barriers per phase, serializing it against the
// MFMA bursts (2 waves/SIMD -> no cross-wave overlap). Now L0(ph+1) is
// issued into pA[pb^1] BEFORE the MFMA work on pA[pb]; one barrier per
// phase. VALU/global-load work hides under the matrix pipe. FP math
// untouched -> absmax must stay exactly 64.0.
__global__ __launch_bounds__(512, 1) void k_mlp_v6(
    const float* __restrict__ x,  const float* __restrict__ W0,
    const float* __restrict__ b0, const float* __restrict__ W1,
    const float* __restrict__ b1, const float* __restrict__ W2,
    const float* __restrict__ b2, float* __restrict__ slater)
{
    __shared__ __align__(16) short pA[2][3][2][4][128][8];  // 96 KB (dbuf)
    __shared__ float s_red[8][128];                         // 4 KB
    const int bid  = blockIdx.x;
    const int xcd  = bid & 7;
    const int jj   = bid >> 3;
    const int half = jj & 1;
    const int w    = (xcd << 5) + (jj >> 1);
    const int tid  = threadIdx.x;
    const int wid  = tid >> 6;     // wave 0..7 -> f-slice wid*64
    const int l    = tid & 63;
    const int col  = l & 15;
    const int g    = l >> 4;
    const int fb   = wid * 64;

    f32x4v acc[8][4];
    #pragma unroll
    for (int bt = 0; bt < 8; ++bt)
        #pragma unroll
        for (int ft = 0; ft < 4; ++ft)
            acc[bt][ft] = (f32x4v){0.f, 0.f, 0.f, 0.f};

    // layer-0 mapping: 64 c x 128 b per phase, 16 per thread
    const int bb = tid & 127;
    const int co = tid >> 7;       // 0..3 (wave-pair uniform)
    const int bg = half*128 + bb;
    const float x0 = x[bg*3+0], x1 = x[bg*3+1], x2 = x[bg*3+2];
    const float* W0w = W0 + (size_t)w*3*HID;
    const float* b0w = b0 + (size_t)w*HID;
    // per-lane B base: 4 consecutive f (one float4) covering ft=0..3
    const float* w1c = W1 + (size_t)w*HID*HID + fb + 4*col;

    // layer 0 for phase ph -> buffer pb
    auto L0 = [&](int ph, int pb) {
        #pragma unroll 4
        for (int pass = 0; pass < 16; ++pass) {
            int cl = co + 4*pass;          // 0..63
            int c  = ph*64 + cl;
            float v = x0*W0w[c] + x1*W0w[HID+c] + x2*W0w[2*HID+c] + b0w[c];
            float t = tanhf(v);
            short h, m, lo; split3(t, h, m, lo);
            int ks = cl >> 5, r32 = cl & 31;
            int gg = (r32 >> 2) & 3;
            int jv = (r32 & 3) + 4*(r32 >> 4);
            pA[pb][0][ks][gg][bb][jv] = h;
            pA[pb][1][ks][gg][bb][jv] = m;
            pA[pb][2][ks][gg][bb][jv] = lo;
        }
    };

    // prologue: phase 0 into buffer 0
    L0(0, 0);
    __syncthreads();

    for (int ph = 0; ph < 8; ++ph) {
        const int pb = ph & 1;
        // issue next phase's layer-0 first: its global loads + VALU overlap
        // the MFMA burst below (different LDS buffer, no dependency)
        if (ph < 7) L0(ph + 1, pb ^ 1);

        #pragma unroll
        for (int ks = 0; ks < 2; ++ks) {
            // ---- B: 8 float4 loads (one per k-row), split -> all 4 ft ----
            bf16x8 Bh[4], Bm[4], Bl[4];
            const float* bkp = w1c + (size_t)(ph*64 + ks*32 + 4*g)*HID;
            #pragma unroll
            for (int j = 0; j < 8; ++j) {
                int koff = (j&3) + 16*(j>>2);
                float4 bv = *reinterpret_cast<const float4*>(bkp + (size_t)koff*HID);
                short h, m, lo;
                split3(bv.x, h, m, lo); Bh[0][j]=h; Bm[0][j]=m; Bl[0][j]=lo;
                split3(bv.y, h, m, lo); Bh[1][j]=h; Bm[1][j]=m; Bl[1][j]=lo;
                split3(bv.z, h, m, lo); Bh[2][j]=h; Bm[2][j]=m; Bl[2][j]=lo;
                split3(bv.w, h, m, lo); Bh[3][j]=h; Bm[3][j]=m; Bl[3][j]=lo;
            }
            // ---- A-frags in 2 chunks of 4 bt; 6-product MFMA ----
            #pragma unroll
            for (int btc = 0; btc < 2; ++btc) {
                bf16x8 Ah[4], Am[4], Al[4];
                #pragma unroll
                for (int b4 = 0; b4 < 4; ++b4) {
                    int row = (btc*4 + b4)*16 + col;
                    Ah[b4] = *reinterpret_cast<const bf16x8*>(&pA[pb][0][ks][g][row][0]);
                    Am[b4] = *reinterpret_cast<const bf16x8*>(&pA[pb][1][ks][g][row][0]);
                    Al[b4] = *reinterpret_cast<const bf16x8*>(&pA[pb][2][ks][g][row][0]);
                }
                #pragma unroll
                for (int b4 = 0; b4 < 4; ++b4) {
                    const int bt = btc*4 + b4;
                    #pragma unroll
                    for (int ft = 0; ft < 4; ++ft) {
                        acc[bt][ft] = __builtin_amdgcn_mfma_f32_16x16x32_bf16(Ah[b4], Bh[ft], acc[bt][ft], 0,0,0);
                        acc[bt][ft] = __builtin_amdgcn_mfma_f32_16x16x32_bf16(Ah[b4], Bm[ft], acc[bt][ft], 0,0,0);
                        acc[bt][ft] = __builtin_amdgcn_mfma_f32_16x16x32_bf16(Am[b4], Bh[ft], acc[bt][ft], 0,0,0);
                        acc[bt][ft] = __builtin_amdgcn_mfma_f32_16x16x32_bf16(Ah[b4], Bl[ft], acc[bt][ft], 0,0,0);
                        acc[bt][ft] = __builtin_amdgcn_mfma_f32_16x16x32_bf16(Am[b4], Bm[ft], acc[bt][ft], 0,0,0);
                        acc[bt][ft] = __builtin_amdgcn_mfma_f32_16x16x32_bf16(Al[b4], Bh[ft], acc[bt][ft], 0,0,0);
                    }
                }
            }
        }
        __syncthreads();   // pb^1 writes visible for next phase; pb reads done
    }

    // ---- epilogue: tanh(acc+b1).W2, reduce over f, write slater row ----
    const float* b1w = b1 + (size_t)w*HID + fb + 4*col;
    const float* W2w = W2 + (size_t)w*HID + fb + 4*col;
    float4 bb4 = *reinterpret_cast<const float4*>(b1w);
    float4 wt4 = *reinterpret_cast<const float4*>(W2w);
    float bbv[4] = {bb4.x, bb4.y, bb4.z, bb4.w};
    float wtv[4] = {wt4.x, wt4.y, wt4.z, wt4.w};
    #pragma unroll
    for (int bt = 0; bt < 8; ++bt)
        #pragma unroll
        for (int r = 0; r < 4; ++r) {
            float part = 0.f;
            #pragma unroll
            for (int ft = 0; ft < 4; ++ft)
                part += tanhf(acc[bt][ft][r] + bbv[ft]) * wtv[ft];
            part += __shfl_xor(part, 1); part += __shfl_xor(part, 2);
            part += __shfl_xor(part, 4); part += __shfl_xor(part, 8);
            if (col == 0) s_red[wid][bt*16 + g*4 + r] = part;
        }
    __syncthreads();
    if (tid < 128) {
        float s = 0.f;
        #pragma unroll
        for (int wd = 0; wd < 8; ++wd) s += s_red[wd][tid];
        slater[w*NP + half*128 + tid] = s + b2[w];
    }
}

__device__ __forceinline__ float rf_f32(float x) {
    return __uint_as_float(__builtin_amdgcn_readfirstlane(__float_as_uint(x)));
}
__device__ __forceinline__ float rl_f32(float x, int lane) {
    return __uint_as_float(__builtin_amdgcn_readlane(__float_as_uint(x), lane));
}
template<int CTRL>
__device__ __forceinline__ unsigned dpp_u32(unsigned v) {
    return (unsigned)__builtin_amdgcn_update_dpp(0, (int)v, CTRL, 0xF, 0xF, true);
}

// Blocked (KB=8) partially-pivoted f32 LU with panel lookahead.
// Byte-identical to the passing round-21/22 version (348 us, absmax 64.0).
__global__ __launch_bounds__(512, 1) void k_lu_blk(const float* __restrict__ A,
                                                   float* __restrict__ out)
{
    const int tid  = threadIdx.x;
    const int ln   = tid & 63;      // lane: row-in-quarter
    const int wv   = tid >> 6;      // wave id = 32-col slice (wave-uniform)
    const int cb   = wv * 32;       // col base

    __shared__ float s_panel[2][NP][KB+1];  // double-buffered, stride 9
    __shared__ float s_stage[2*KB][260];
    __shared__ float s_U[KB][260];
    __shared__ int   s_src[NP];
    __shared__ int   s_p[KB];
    __shared__ int   s_uslot[KB];
    __shared__ float s_piv[NP];

    float a[4][32];                       // rows q*64+ln, cols cb..cb+31
    {
        const float4* Ap = reinterpret_cast<const float4*>(A);
        #pragma unroll
        for (int q = 0; q < 4; ++q)
            #pragma unroll
            for (int u = 0; u < 8; ++u) {
                float4 v = Ap[(q*64+ln)*64 + wv*8 + u];
                a[q][u*4+0]=v.x; a[q][u*4+1]=v.y; a[q][u*4+2]=v.z; a[q][u*4+3]=v.w;
            }
    }

    // stage cols [k0s, k0s+8) of this wave's slice into spnl (caller guards wave)
    auto STAGE = [&](int k0s, float (*spnl)[KB+1]) {
        switch ((k0s & 31) >> 3) {
            case 0:
                #pragma unroll
                for (int q = 0; q < 4; ++q)
                    #pragma unroll
                    for (int c = 0; c < KB; ++c) spnl[q*64+ln][c] = a[q][c];
                break;
            case 1:
                #pragma unroll
                for (int q = 0; q < 4; ++q)
                    #pragma unroll
                    for (int c = 0; c < KB; ++c) spnl[q*64+ln][c] = a[q][8+c];
                break;
            case 2:
                #pragma unroll
                for (int q = 0; q < 4; ++q)
                    #pragma unroll
                    for (int c = 0; c < KB; ++c) spnl[q*64+ln][c] = a[q][16+c];
                break;
            default:
                #pragma unroll
                for (int q = 0; q < 4; ++q)
                    #pragma unroll
                    for (int c = 0; c < KB; ++c) spnl[q*64+ln][c] = a[q][24+c];
                break;
        }
    };

    // wave-0 panel factorization (r15 STEP2; uslot lookup first-match)
    auto STEP2 = [&](int k0, float (*spnl)[KB+1]) {
        const int lane = tid;
        float pa[4][KB];
        int   lid[4];
        #pragma unroll
        for (int q = 0; q < 4; ++q) {
            lid[q] = q*64 + lane;
            #pragma unroll
            for (int c = 0; c < KB; ++c) pa[q][c] = spnl[q*64+lane][c];
        }
        int pvt[KB];
        #pragma unroll
        for (int kk = 0; kk < KB; ++kk) {
            const int k = k0 + kk;
            unsigned key = 0u;
            #pragma unroll
            for (int q = 0; q < 4; ++q) {
                unsigned ab = __float_as_uint(pa[q][kk]) & 0x7FFFFFFFu;
                unsigned kq = (ab & 0xFFFFFF00u) | (unsigned)(255 - lid[q]);
                if (lid[q] >= k && kq > key) key = kq;
            }
            { unsigned t;
              t = dpp_u32<0x111>(key); if (t > key) key = t;
              t = dpp_u32<0x112>(key); if (t > key) key = t;
              t = dpp_u32<0x114>(key); if (t > key) key = t;
              t = dpp_u32<0x118>(key); if (t > key) key = t;
              t = dpp_u32<0x142>(key); if (t > key) key = t;
              t = dpp_u32<0x143>(key); if (t > key) key = t;
            }
            const unsigned gk = (unsigned)__builtin_amdgcn_readlane((int)key, 63);
            const int p = 255 - (int)(gk & 0xFFu);
            pvt[kk] = p;
            int myslot = -1;
            #pragma unroll
            for (int q = 0; q < 4; ++q) if (lid[q] == p) myslot = q;
            unsigned long long bal = __ballot(myslot >= 0);
            const int plane = (int)__ffsll((long long)bal) - 1;
            const int pslot = __builtin_amdgcn_readlane(myslot, plane);
            float urow[KB];
            #pragma unroll
            for (int c = 0; c < KB; ++c) {
                float t = (pslot==0) ? pa[0][c] : (pslot==1) ? pa[1][c]
                        : (pslot==2) ? pa[2][c] : pa[3][c];
                urow[c] = rl_f32(t, plane);
            }
            #pragma unroll
            for (int q = 0; q < 4; ++q) {
                int lq = lid[q];
                lid[q] = (lq == k) ? p : (lq == p) ? k : lq;
            }
            const float pv = urow[kk];
            if (lane == 0) s_piv[k] = (p != k) ? -pv : pv;
            const float rp = rf_f32(1.0f / pv);
            #pragma unroll
            for (int q = 0; q < 4; ++q)
                if (lid[q] > k) pa[q][kk] *= rp;
            #pragma unroll
            for (int c = kk+1; c < KB; ++c) {
                #pragma unroll
                for (int q = 0; q < 4; ++q)
                    if (lid[q] > k) pa[q][c] = fmaf(-pa[q][kk], urow[c], pa[q][c]);
            }
        }
        #pragma unroll
        for (int q = 0; q < 4; ++q)
            #pragma unroll
            for (int c = 0; c < KB; ++c) spnl[lid[q]][c] = pa[q][c];
        if (lane == 0) {
            s_p[0]=pvt[0]; s_p[1]=pvt[1]; s_p[2]=pvt[2]; s_p[3]=pvt[3];
            s_p[4]=pvt[4]; s_p[5]=pvt[5]; s_p[6]=pvt[6]; s_p[7]=pvt[7];
        }
        // in-register swap simulation on 16 tracked positions
        int l8 = lane - 8;
        int psel = pvt[0];
        psel = (l8==1)?pvt[1]:psel; psel = (l8==2)?pvt[2]:psel;
        psel = (l8==3)?pvt[3]:psel; psel = (l8==4)?pvt[4]:psel;
        psel = (l8==5)?pvt[5]:psel; psel = (l8==6)?pvt[6]:psel;
        psel = (l8==7)?pvt[7]:psel;
        const int mypos = (lane < 8) ? (k0 + lane) : psel;
        int cur = mypos;
        #pragma unroll
        for (int s = 0; s < KB; ++s) {
            int cA = __builtin_amdgcn_readlane(cur, s);
            int cB = __builtin_amdgcn_readlane(cur, 8+s);
            int ks = k0 + s, ps = pvt[s];
            if (mypos == ks) cur = cB;
            else if (mypos == ps) cur = cA;
        }
        if (lane < 16) s_src[mypos] = cur;
        if (lane < 8) {
            int c = cur, slot = 8;
            // descending -> FIRST matching s wins (duplicate-safe)
            slot = (pvt[7]==c)?15:slot; slot = (pvt[6]==c)?14:slot;
            slot = (pvt[5]==c)?13:slot; slot = (pvt[4]==c)?12:slot;
            slot = (pvt[3]==c)?11:slot; slot = (pvt[2]==c)?10:slot;
            slot = (pvt[1]==c)? 9:slot; slot = (pvt[0]==c)? 8:slot;
            if (c >= k0 && c < k0+KB) slot = c - k0;
            s_uslot[lane] = slot;
        }
    };

    // ---- prologue: stage + factorize panel 0 ----
    if (tid < 256) s_src[tid] = tid;
    if (wv == 0) STAGE(0, s_panel[0]);
    __syncthreads();
    if (tid < 64) STEP2(0, s_panel[0]);
    __syncthreads();

    for (int pi = 0; pi < 31; ++pi) {
        const int k0  = pi * KB;
        const int buf = pi & 1;
        const int nk  = k0 + KB;

        int pp[KB];
        #pragma unroll
        for (int s = 0; s < KB; ++s) pp[s] = s_p[s];

        // ---- STEP 3: stage affected rows (lane-parallel, first-match) ----
        #pragma unroll
        for (int q = 0; q < 4; ++q) {
            const int iq = q*64 + ln;
            const bool inpanel = (iq >= k0 && iq < nk);
            if (inpanel) {
                const int sl = iq - k0;
                #pragma unroll
                for (int u = 0; u < 8; ++u) {
                    float4 v; v.x=a[q][u*4+0]; v.y=a[q][u*4+1];
                    v.z=a[q][u*4+2]; v.w=a[q][u*4+3];
                    *reinterpret_cast<float4*>(&s_stage[sl][cb + u*4]) = v;
                }
            }
            // first-match pivot slot; panel-range rows excluded (slots unread)
            int sl2 = -1;
            #pragma unroll
            for (int s = KB-1; s >= 0; --s) if (pp[s] == iq) sl2 = KB + s;
            if (sl2 >= 0 && !inpanel) {
                #pragma unroll
                for (int u = 0; u < 8; ++u) {
                    float4 v; v.x=a[q][u*4+0]; v.y=a[q][u*4+1];
                    v.z=a[q][u*4+2]; v.w=a[q][u*4+3];
                    *reinterpret_cast<float4*>(&s_stage[sl2][cb + u*4]) = v;
                }
            }
        }
        __syncthreads();                                  // B3

        // ---- STEP 4a: apply row permutation (first-match lookup) ----
        #pragma unroll
        for (int q = 0; q < 4; ++q) {
            const int iq = q*64 + ln;
            const int sr = s_src[iq];
            if (sr != iq) {
                int slot = KB;
                #pragma unroll
                for (int s = KB-1; s >= 0; --s) slot = (pp[s]==sr) ? KB+s : slot;
                if (sr >= k0 && sr < nk) slot = sr - k0;
                #pragma unroll
                for (int u = 0; u < 8; ++u) {
                    float4 v = *reinterpret_cast<const float4*>(&s_stage[slot][cb + u*4]);
                    a[q][u*4+0]=v.x; a[q][u*4+1]=v.y; a[q][u*4+2]=v.z; a[q][u*4+3]=v.w;
                }
            }
        }
        // ---- STEP 4b: TRSM of U block, column-parallel (tid<256) ----
        if (tid < 256) {
            const int j = tid;
            int us[KB];
            #pragma unroll
            for (int m = 0; m < KB; ++m) us[m] = s_uslot[m];
            float uv[KB];
            #pragma unroll
            for (int m = 0; m < KB; ++m) {
                float v = s_stage[us[m]][j];
                #pragma unroll
                for (int s = 0; s < KB; ++s)
                    if (s < m) v = fmaf(-s_panel[buf][k0+m][s], uv[s], v);
                uv[m] = v;
                s_U[m][j] = v;
            }
        }
        __syncthreads();                                  // B4

        // ---- STEP 5a: owner wave updates next-panel cols [nk, nk+8),
        //      stages them into s_panel[buf^1]; s_src re-init ----
        if (tid < 256) s_src[tid] = tid;
        if (wv == (nk >> 5)) {
            float L0v[4][KB];
            #pragma unroll
            for (int q = 0; q < 4; ++q)
                #pragma unroll
                for (int m = 0; m < KB; ++m) L0v[q][m] = s_panel[buf][q*64+ln][m];
            #pragma unroll
            for (int u4 = 0; u4 < 8; ++u4) {
                if (cb + u4*4 >= nk && cb + u4*4 < nk + KB) {   // wave-uniform
                    #pragma unroll
                    for (int m = 0; m < KB; ++m) {
                        const float4 uvv = *reinterpret_cast<const float4*>(&s_U[m][cb + u4*4]);
                        #pragma unroll
                        for (int q = 0; q < 4; ++q) {
                            if (q*64 + 63 >= nk) {              // wave-uniform
                                a[q][u4*4+0] = fmaf(-L0v[q][m], uvv.x, a[q][u4*4+0]);
                                a[q][u4*4+1] = fmaf(-L0v[q][m], uvv.y, a[q][u4*4+1]);
                                a[q][u4*4+2] = fmaf(-L0v[q][m], uvv.z, a[q][u4*4+2]);
                                a[q][u4*4+3] = fmaf(-L0v[q][m], uvv.w, a[q][u4*4+3]);
                            }
                        }
                    }
                }
            }
            STAGE(nk, s_panel[buf ^ 1]);
        }
        __syncthreads();                                  // B5

        // ---- wave0: STEP2(next panel)  ||  all waves: STEP5b ----
        if (tid < 64) STEP2(nk, s_panel[buf ^ 1]);
        if (cb + 31 >= nk + KB) {                         // wave-uniform
            float L0v[4][KB];
            #pragma unroll
            for (int q = 0; q < 4; ++q)
                #pragma unroll
                for (int m = 0; m < KB; ++m) L0v[q][m] = s_panel[buf][q*64+ln][m];
            #pragma unroll
            for (int u4 = 0; u4 < 8; ++u4) {
                if (cb + u4*4 >= nk + KB) {               // wave-uniform
                    #pragma unroll
                    for (int m = 0; m < KB; ++m) {
                        const float4 uvv = *reinterpret_cast<const float4*>(&s_U[m][cb + u4*4]);
                        #pragma unroll
                        for (int q = 0; q < 4; ++q) {
                            if (q*64 + 63 >= nk) {        // wave-uniform
                                a[q][u4*4+0] = fmaf(-L0v[q][m], uvv.x, a[q][u4*4+0]);
                                a[q][u4*4+1] = fmaf(-L0v[q][m], uvv.y, a[q][u4*4+1]);
                                a[q][u4*4+2] = fmaf(-L0v[q][m], uvv.z, a[q][u4*4+2]);
                                a[q][u4*4+3] = fmaf(-L0v[q][m], uvv.w, a[q][u4*4+3]);
                            }
                        }
                    }
                }
            }
        }
        __syncthreads();                                  // B6
    }

    // ---- logdet = sum log|piv| (f64 accum), sign = parity of negatives ----
    if (tid < 64) {
        double ld = 0.0; int neg = 0;
        #pragma unroll
        for (int q = 0; q < 4; ++q) {
            float pv = s_piv[q*64 + tid];
            ld  += (double)logf(fabsf(pv));
            neg ^= (pv < 0.0f) ? 1 : 0;
        }
        #pragma unroll
        for (int off = 32; off; off >>= 1) {
            ld  += __shfl_xor(ld, off);
            neg ^= __shfl_xor(neg, off);
        }
        if (tid == 0) { out[0] = neg ? -1.0f : 1.0f; out[1] = (float)ld; }
    }
}

extern "C" void kernel_launch(void* const* d_in, const int* in_sizes, int n_in,
                              void* d_out, int out_size, void* d_ws, size_t ws_size,
                              hipStream_t stream)
{
    const float* x  = (const float*)d_in[0];
    const float* W0 = (const float*)d_in[1];
    const float* b0 = (const float*)d_in[2];
    const float* W1 = (const float*)d_in[3];
    const float* b1 = (const float*)d_in[4];
    const float* W2 = (const float*)d_in[5];
    const float* b2 = (const float*)d_in[6];
    float* out    = (float*)d_out;
    float* slater = (float*)d_ws;           // 256*256*4 = 256 KB scratch

    k_mlp_v6<<<512, 512, 0, stream>>>(x, W0, b0, W1, b1, W2, b2, slater);
    k_lu_blk<<<1, 512, 0, stream>>>(slater, out);
}

// Round 24
// 593.326 us; speedup vs baseline: 1.0125x; 1.0125x over previous
//
#include <hip/hip_runtime.h>
#include <math.h>

#define NP 256
#define HID 512
#define KB 8        // LU panel width

typedef short bf16x8 __attribute__((ext_vector_type(8)));
typedef float f32x4v __attribute__((ext_vector_type(4)));

// RNE bf16 with exact residual (v - bf16(v) is exactly representable).
__device__ __forceinline__ short bf16_rne(float v, float& rem) {
    unsigned u = __float_as_uint(v);
    unsigned r = (u + 0x7FFFu + ((u >> 16) & 1u)) & 0xFFFF0000u;
    rem = v - __uint_as_float(r);
    return (short)(r >> 16);
}
// 3-way RNE split: v = h + m + lo + r3, |r3| <= 2^-27 |v| (unbiased).
__device__ __forceinline__ void split3(float v, short& h, short& m, short& lo) {
    float r1, r2;
    h = bf16_rne(v, r1);
    m = bf16_rne(r1, r2);
    unsigned u2 = __float_as_uint(r2);
    lo = (short)((u2 + 0x7FFFu + ((u2 >> 16) & 1u)) >> 16);
}

// v5 MLP (byte-identical to passing r22, the session best): B-tile remap
// f = fb+4*col+ft with coalesced float4 B loads; h0 split once into packed
// A-frags in LDS (52 KB -> 2 blocks/CU co-resident, giving cross-block
// L0/MFMA overlap); product-outer MFMA schedule.
__global__ __launch_bounds__(512, 1) void k_mlp_v5(
    const float* __restrict__ x,  const float* __restrict__ W0,
    const float* __restrict__ b0, const float* __restrict__ W1,
    const float* __restrict__ b1, const float* __restrict__ W2,
    const float* __restrict__ b2, float* __restrict__ slater)
{
    __shared__ __align__(16) short pA[3][2][4][128][8];  // 48 KB
    __shared__ float s_red[8][128];                      // 4 KB
    const int bid  = blockIdx.x;
    const int xcd  = bid & 7;
    const int jj   = bid >> 3;
    const int half = jj & 1;
    const int w    = (xcd << 5) + (jj >> 1);
    const int tid  = threadIdx.x;
    const int wid  = tid >> 6;     // wave 0..7 -> f-slice wid*64
    const int l    = tid & 63;
    const int col  = l & 15;
    const int g    = l >> 4;
    const int fb   = wid * 64;

    f32x4v acc[8][4];
    #pragma unroll
    for (int bt = 0; bt < 8; ++bt)
        #pragma unroll
        for (int ft = 0; ft < 4; ++ft)
            acc[bt][ft] = (f32x4v){0.f, 0.f, 0.f, 0.f};

    // layer-0 mapping: 64 c x 128 b per phase, 16 per thread
    const int bb = tid & 127;
    const int co = tid >> 7;       // 0..3 (wave-pair uniform)
    const int bg = half*128 + bb;
    const float x0 = x[bg*3+0], x1 = x[bg*3+1], x2 = x[bg*3+2];
    const float* W0w = W0 + (size_t)w*3*HID;
    const float* b0w = b0 + (size_t)w*HID;
    // per-lane B base: 4 consecutive f (one float4) covering ft=0..3
    const float* w1c = W1 + (size_t)w*HID*HID + fb + 4*col;

    for (int ph = 0; ph < 8; ++ph) {
        if (ph) __syncthreads();
        // ---- layer 0: split h0 once into packed A-frags ----
        #pragma unroll 4
        for (int pass = 0; pass < 16; ++pass) {
            int cl = co + 4*pass;          // 0..63
            int c  = ph*64 + cl;
            float v = x0*W0w[c] + x1*W0w[HID+c] + x2*W0w[2*HID+c] + b0w[c];
            float t = tanhf(v);
            short h, m, lo; split3(t, h, m, lo);
            int ks = cl >> 5, r32 = cl & 31;
            int gg = (r32 >> 2) & 3;
            int jv = (r32 & 3) + 4*(r32 >> 4);
            pA[0][ks][gg][bb][jv] = h;
            pA[1][ks][gg][bb][jv] = m;
            pA[2][ks][gg][bb][jv] = lo;
        }
        __syncthreads();

        #pragma unroll
        for (int ks = 0; ks < 2; ++ks) {
            // ---- B: 8 float4 loads (one per k-row), split -> all 4 ft ----
            bf16x8 Bh[4], Bm[4], Bl[4];
            const float* bkp = w1c + (size_t)(ph*64 + ks*32 + 4*g)*HID;
            #pragma unroll
            for (int j = 0; j < 8; ++j) {
                int koff = (j&3) + 16*(j>>2);
                float4 bv = *reinterpret_cast<const float4*>(bkp + (size_t)koff*HID);
                short h, m, lo;
                split3(bv.x, h, m, lo); Bh[0][j]=h; Bm[0][j]=m; Bl[0][j]=lo;
                split3(bv.y, h, m, lo); Bh[1][j]=h; Bm[1][j]=m; Bl[1][j]=lo;
                split3(bv.z, h, m, lo); Bh[2][j]=h; Bm[2][j]=m; Bl[2][j]=lo;
                split3(bv.w, h, m, lo); Bh[3][j]=h; Bm[3][j]=m; Bl[3][j]=lo;
            }
            // ---- A-frags in 2 chunks of 4 bt; PRODUCT-OUTER MFMA ----
            #pragma unroll
            for (int btc = 0; btc < 2; ++btc) {
                bf16x8 Ah[4], Am[4], Al[4];
                #pragma unroll
                for (int b4 = 0; b4 < 4; ++b4) {
                    int row = (btc*4 + b4)*16 + col;
                    Ah[b4] = *reinterpret_cast<const bf16x8*>(&pA[0][ks][g][row][0]);
                    Am[b4] = *reinterpret_cast<const bf16x8*>(&pA[1][ks][g][row][0]);
                    Al[b4] = *reinterpret_cast<const bf16x8*>(&pA[2][ks][g][row][0]);
                }
                // product 1: Ah*Bh  (16 independent MFMAs)
                #pragma unroll
                for (int b4 = 0; b4 < 4; ++b4)
                    #pragma unroll
                    for (int ft = 0; ft < 4; ++ft)
                        acc[btc*4+b4][ft] = __builtin_amdgcn_mfma_f32_16x16x32_bf16(Ah[b4], Bh[ft], acc[btc*4+b4][ft], 0,0,0);
                // product 2: Ah*Bm
                #pragma unroll
                for (int b4 = 0; b4 < 4; ++b4)
                    #pragma unroll
                    for (int ft = 0; ft < 4; ++ft)
                        acc[btc*4+b4][ft] = __builtin_amdgcn_mfma_f32_16x16x32_bf16(Ah[b4], Bm[ft], acc[btc*4+b4][ft], 0,0,0);
                // product 3: Am*Bh
                #pragma unroll
                for (int b4 = 0; b4 < 4; ++b4)
                    #pragma unroll
                    for (int ft = 0; ft < 4; ++ft)
                        acc[btc*4+b4][ft] = __builtin_amdgcn_mfma_f32_16x16x32_bf16(Am[b4], Bh[ft], acc[btc*4+b4][ft], 0,0,0);
                // product 4: Ah*Bl
                #pragma unroll
                for (int b4 = 0; b4 < 4; ++b4)
                    #pragma unroll
                    for (int ft = 0; ft < 4; ++ft)
                        acc[btc*4+b4][ft] = __builtin_amdgcn_mfma_f32_16x16x32_bf16(Ah[b4], Bl[ft], acc[btc*4+b4][ft], 0,0,0);
                // product 5: Am*Bm
                #pragma unroll
                for (int b4 = 0; b4 < 4; ++b4)
                    #pragma unroll
                    for (int ft = 0; ft < 4; ++ft)
                        acc[btc*4+b4][ft] = __builtin_amdgcn_mfma_f32_16x16x32_bf16(Am[b4], Bm[ft], acc[btc*4+b4][ft], 0,0,0);
                // product 6: Al*Bh
                #pragma unroll
                for (int b4 = 0; b4 < 4; ++b4)
                    #pragma unroll
                    for (int ft = 0; ft < 4; ++ft)
                        acc[btc*4+b4][ft] = __builtin_amdgcn_mfma_f32_16x16x32_bf16(Al[b4], Bh[ft], acc[btc*4+b4][ft], 0,0,0);
            }
        }
    }

    // ---- epilogue: tanh(acc+b1).W2, reduce over f, write slater row ----
    const float* b1w = b1 + (size_t)w*HID + fb + 4*col;
    const float* W2w = W2 + (size_t)w*HID + fb + 4*col;
    float4 bb4 = *reinterpret_cast<const float4*>(b1w);
    float4 wt4 = *reinterpret_cast<const float4*>(W2w);
    float bbv[4] = {bb4.x, bb4.y, bb4.z, bb4.w};
    float wtv[4] = {wt4.x, wt4.y, wt4.z, wt4.w};
    #pragma unroll
    for (int bt = 0; bt < 8; ++bt)
        #pragma unroll
        for (int r = 0; r < 4; ++r) {
            float part = 0.f;
            #pragma unroll
            for (int ft = 0; ft < 4; ++ft)
                part += tanhf(acc[bt][ft][r] + bbv[ft]) * wtv[ft];
            part += __shfl_xor(part, 1); part += __shfl_xor(part, 2);
            part += __shfl_xor(part, 4); part += __shfl_xor(part, 8);
            if (col == 0) s_red[wid][bt*16 + g*4 + r] = part;
        }
    __syncthreads();
    if (tid < 128) {
        float s = 0.f;
        #pragma unroll
        for (int wd = 0; wd < 8; ++wd) s += s_red[wd][tid];
        slater[w*NP + half*128 + tid] = s + b2[w];
    }
}

__device__ __forceinline__ float rf_f32(float x) {
    return __uint_as_float(__builtin_amdgcn_readfirstlane(__float_as_uint(x)));
}
__device__ __forceinline__ float rl_f32(float x, int lane) {
    return __uint_as_float(__builtin_amdgcn_readlane(__float_as_uint(x), lane));
}
template<int CTRL>
__device__ __forceinline__ unsigned dpp_u32(unsigned v) {
    return (unsigned)__builtin_amdgcn_update_dpp(0, (int)v, CTRL, 0xF, 0xF, true);
}

// Blocked (KB=8) partially-pivoted f32 LU with panel lookahead.
// Byte-identical to the passing round-21/22 version (~347 us, absmax 64.0).
__global__ __launch_bounds__(512, 1) void k_lu_blk(const float* __restrict__ A,
                                                   float* __restrict__ out)
{
    const int tid  = threadIdx.x;
    const int ln   = tid & 63;      // lane: row-in-quarter
    const int wv   = tid >> 6;      // wave id = 32-col slice (wave-uniform)
    const int cb   = wv * 32;       // col base

    __shared__ float s_panel[2][NP][KB+1];  // double-buffered, stride 9
    __shared__ float s_stage[2*KB][260];
    __shared__ float s_U[KB][260];
    __shared__ int   s_src[NP];
    __shared__ int   s_p[KB];
    __shared__ int   s_uslot[KB];
    __shared__ float s_piv[NP];

    float a[4][32];                       // rows q*64+ln, cols cb..cb+31
    {
        const float4* Ap = reinterpret_cast<const float4*>(A);
        #pragma unroll
        for (int q = 0; q < 4; ++q)
            #pragma unroll
            for (int u = 0; u < 8; ++u) {
                float4 v = Ap[(q*64+ln)*64 + wv*8 + u];
                a[q][u*4+0]=v.x; a[q][u*4+1]=v.y; a[q][u*4+2]=v.z; a[q][u*4+3]=v.w;
            }
    }

    // stage cols [k0s, k0s+8) of this wave's slice into spnl (caller guards wave)
    auto STAGE = [&](int k0s, float (*spnl)[KB+1]) {
        switch ((k0s & 31) >> 3) {
            case 0:
                #pragma unroll
                for (int q = 0; q < 4; ++q)
                    #pragma unroll
                    for (int c = 0; c < KB; ++c) spnl[q*64+ln][c] = a[q][c];
                break;
            case 1:
                #pragma unroll
                for (int q = 0; q < 4; ++q)
                    #pragma unroll
                    for (int c = 0; c < KB; ++c) spnl[q*64+ln][c] = a[q][8+c];
                break;
            case 2:
                #pragma unroll
                for (int q = 0; q < 4; ++q)
                    #pragma unroll
                    for (int c = 0; c < KB; ++c) spnl[q*64+ln][c] = a[q][16+c];
                break;
            default:
                #pragma unroll
                for (int q = 0; q < 4; ++q)
                    #pragma unroll
                    for (int c = 0; c < KB; ++c) spnl[q*64+ln][c] = a[q][24+c];
                break;
        }
    };

    // wave-0 panel factorization (r15 STEP2; uslot lookup first-match)
    auto STEP2 = [&](int k0, float (*spnl)[KB+1]) {
        const int lane = tid;
        float pa[4][KB];
        int   lid[4];
        #pragma unroll
        for (int q = 0; q < 4; ++q) {
            lid[q] = q*64 + lane;
            #pragma unroll
            for (int c = 0; c < KB; ++c) pa[q][c] = spnl[q*64+lane][c];
        }
        int pvt[KB];
        #pragma unroll
        for (int kk = 0; kk < KB; ++kk) {
            const int k = k0 + kk;
            unsigned key = 0u;
            #pragma unroll
            for (int q = 0; q < 4; ++q) {
                unsigned ab = __float_as_uint(pa[q][kk]) & 0x7FFFFFFFu;
                unsigned kq = (ab & 0xFFFFFF00u) | (unsigned)(255 - lid[q]);
                if (lid[q] >= k && kq > key) key = kq;
            }
            { unsigned t;
              t = dpp_u32<0x111>(key); if (t > key) key = t;
              t = dpp_u32<0x112>(key); if (t > key) key = t;
              t = dpp_u32<0x114>(key); if (t > key) key = t;
              t = dpp_u32<0x118>(key); if (t > key) key = t;
              t = dpp_u32<0x142>(key); if (t > key) key = t;
              t = dpp_u32<0x143>(key); if (t > key) key = t;
            }
            const unsigned gk = (unsigned)__builtin_amdgcn_readlane((int)key, 63);
            const int p = 255 - (int)(gk & 0xFFu);
            pvt[kk] = p;
            int myslot = -1;
            #pragma unroll
            for (int q = 0; q < 4; ++q) if (lid[q] == p) myslot = q;
            unsigned long long bal = __ballot(myslot >= 0);
            const int plane = (int)__ffsll((long long)bal) - 1;
            const int pslot = __builtin_amdgcn_readlane(myslot, plane);
            float urow[KB];
            #pragma unroll
            for (int c = 0; c < KB; ++c) {
                float t = (pslot==0) ? pa[0][c] : (pslot==1) ? pa[1][c]
                        : (pslot==2) ? pa[2][c] : pa[3][c];
                urow[c] = rl_f32(t, plane);
            }
            #pragma unroll
            for (int q = 0; q < 4; ++q) {
                int lq = lid[q];
                lid[q] = (lq == k) ? p : (lq == p) ? k : lq;
            }
            const float pv = urow[kk];
            if (lane == 0) s_piv[k] = (p != k) ? -pv : pv;
            const float rp = rf_f32(1.0f / pv);
            #pragma unroll
            for (int q = 0; q < 4; ++q)
                if (lid[q] > k) pa[q][kk] *= rp;
            #pragma unroll
            for (int c = kk+1; c < KB; ++c) {
                #pragma unroll
                for (int q = 0; q < 4; ++q)
                    if (lid[q] > k) pa[q][c] = fmaf(-pa[q][kk], urow[c], pa[q][c]);
            }
        }
        #pragma unroll
        for (int q = 0; q < 4; ++q)
            #pragma unroll
            for (int c = 0; c < KB; ++c) spnl[lid[q]][c] = pa[q][c];
        if (lane == 0) {
            s_p[0]=pvt[0]; s_p[1]=pvt[1]; s_p[2]=pvt[2]; s_p[3]=pvt[3];
            s_p[4]=pvt[4]; s_p[5]=pvt[5]; s_p[6]=pvt[6]; s_p[7]=pvt[7];
        }
        // in-register swap simulation on 16 tracked positions
        int l8 = lane - 8;
        int psel = pvt[0];
        psel = (l8==1)?pvt[1]:psel; psel = (l8==2)?pvt[2]:psel;
        psel = (l8==3)?pvt[3]:psel; psel = (l8==4)?pvt[4]:psel;
        psel = (l8==5)?pvt[5]:psel; psel = (l8==6)?pvt[6]:psel;
        psel = (l8==7)?pvt[7]:psel;
        const int mypos = (lane < 8) ? (k0 + lane) : psel;
        int cur = mypos;
        #pragma unroll
        for (int s = 0; s < KB; ++s) {
            int cA = __builtin_amdgcn_readlane(cur, s);
            int cB = __builtin_amdgcn_readlane(cur, 8+s);
            int ks = k0 + s, ps = pvt[s];
            if (mypos == ks) cur = cB;
            else if (mypos == ps) cur = cA;
        }
        if (lane < 16) s_src[mypos] = cur;
        if (lane < 8) {
            int c = cur, slot = 8;
            // descending -> FIRST matching s wins (duplicate-safe)
            slot = (pvt[7]==c)?15:slot; slot = (pvt[6]==c)?14:slot;
            slot = (pvt[5]==c)?13:slot; slot = (pvt[4]==c)?12:slot;
            slot = (pvt[3]==c)?11:slot; slot = (pvt[2]==c)?10:slot;
            slot = (pvt[1]==c)? 9:slot; slot = (pvt[0]==c)? 8:slot;
            if (c >= k0 && c < k0+KB) slot = c - k0;
            s_uslot[lane] = slot;
        }
    };

    // ---- prologue: stage + factorize panel 0 ----
    if (tid < 256) s_src[tid] = tid;
    if (wv == 0) STAGE(0, s_panel[0]);
    __syncthreads();
    if (tid < 64) STEP2(0, s_panel[0]);
    __syncthreads();

    for (int pi = 0; pi < 31; ++pi) {
        const int k0  = pi * KB;
        const int buf = pi & 1;
        const int nk  = k0 + KB;

        int pp[KB];
        #pragma unroll
        for (int s = 0; s < KB; ++s) pp[s] = s_p[s];

        // ---- STEP 3: stage affected rows (lane-parallel, first-match) ----
        #pragma unroll
        for (int q = 0; q < 4; ++q) {
            const int iq = q*64 + ln;
            const bool inpanel = (iq >= k0 && iq < nk);
            if (inpanel) {
                const int sl = iq - k0;
                #pragma unroll
                for (int u = 0; u < 8; ++u) {
                    float4 v; v.x=a[q][u*4+0]; v.y=a[q][u*4+1];
                    v.z=a[q][u*4+2]; v.w=a[q][u*4+3];
                    *reinterpret_cast<float4*>(&s_stage[sl][cb + u*4]) = v;
                }
            }
            // first-match pivot slot; panel-range rows excluded (slots unread)
            int sl2 = -1;
            #pragma unroll
            for (int s = KB-1; s >= 0; --s) if (pp[s] == iq) sl2 = KB + s;
            if (sl2 >= 0 && !inpanel) {
                #pragma unroll
                for (int u = 0; u < 8; ++u) {
                    float4 v; v.x=a[q][u*4+0]; v.y=a[q][u*4+1];
                    v.z=a[q][u*4+2]; v.w=a[q][u*4+3];
                    *reinterpret_cast<float4*>(&s_stage[sl2][cb + u*4]) = v;
                }
            }
        }
        __syncthreads();                                  // B3

        // ---- STEP 4a: apply row permutation (first-match lookup) ----
        #pragma unroll
        for (int q = 0; q < 4; ++q) {
            const int iq = q*64 + ln;
            const int sr = s_src[iq];
            if (sr != iq) {
                int slot = KB;
                #pragma unroll
                for (int s = KB-1; s >= 0; --s) slot = (pp[s]==sr) ? KB+s : slot;
                if (sr >= k0 && sr < nk) slot = sr - k0;
                #pragma unroll
                for (int u = 0; u < 8; ++u) {
                    float4 v = *reinterpret_cast<const float4*>(&s_stage[slot][cb + u*4]);
                    a[q][u*4+0]=v.x; a[q][u*4+1]=v.y; a[q][u*4+2]=v.z; a[q][u*4+3]=v.w;
                }
            }
        }
        // ---- STEP 4b: TRSM of U block, column-parallel (tid<256) ----
        if (tid < 256) {
            const int j = tid;
            int us[KB];
            #pragma unroll
            for (int m = 0; m < KB; ++m) us[m] = s_uslot[m];
            float uv[KB];
            #pragma unroll
            for (int m = 0; m < KB; ++m) {
                float v = s_stage[us[m]][j];
                #pragma unroll
                for (int s = 0; s < KB; ++s)
                    if (s < m) v = fmaf(-s_panel[buf][k0+m][s], uv[s], v);
                uv[m] = v;
                s_U[m][j] = v;
            }
        }
        __syncthreads();                                  // B4

        // ---- STEP 5a: owner wave updates next-panel cols [nk, nk+8),
        //      stages them into s_panel[buf^1]; s_src re-init ----
        if (tid < 256) s_src[tid] = tid;
        if (wv == (nk >> 5)) {
            float L0[4][KB];
            #pragma unroll
            for (int q = 0; q < 4; ++q)
                #pragma unroll
                for (int m = 0; m < KB; ++m) L0[q][m] = s_panel[buf][q*64+ln][m];
            #pragma unroll
            for (int u4 = 0; u4 < 8; ++u4) {
                if (cb + u4*4 >= nk && cb + u4*4 < nk + KB) {   // wave-uniform
                    #pragma unroll
                    for (int m = 0; m < KB; ++m) {
                        const float4 uvv = *reinterpret_cast<const float4*>(&s_U[m][cb + u4*4]);
                        #pragma unroll
                        for (int q = 0; q < 4; ++q) {
                            if (q*64 + 63 >= nk) {              // wave-uniform
                                a[q][u4*4+0] = fmaf(-L0[q][m], uvv.x, a[q][u4*4+0]);
                                a[q][u4*4+1] = fmaf(-L0[q][m], uvv.y, a[q][u4*4+1]);
                                a[q][u4*4+2] = fmaf(-L0[q][m], uvv.z, a[q][u4*4+2]);
                                a[q][u4*4+3] = fmaf(-L0[q][m], uvv.w, a[q][u4*4+3]);
                            }
                        }
                    }
                }
            }
            STAGE(nk, s_panel[buf ^ 1]);
        }
        __syncthreads();                                  // B5

        // ---- wave0: STEP2(next panel)  ||  all waves: STEP5b ----
        if (tid < 64) STEP2(nk, s_panel[buf ^ 1]);
        if (cb + 31 >= nk + KB) {                         // wave-uniform
            float L0[4][KB];
            #pragma unroll
            for (int q = 0; q < 4; ++q)
                #pragma unroll
                for (int m = 0; m < KB; ++m) L0[q][m] = s_panel[buf][q*64+ln][m];
            #pragma unroll
            for (int u4 = 0; u4 < 8; ++u4) {
                if (cb + u4*4 >= nk + KB) {               // wave-uniform
                    #pragma unroll
                    for (int m = 0; m < KB; ++m) {
                        const float4 uvv = *reinterpret_cast<const float4*>(&s_U[m][cb + u4*4]);
                        #pragma unroll
                        for (int q = 0; q < 4; ++q) {
                            if (q*64 + 63 >= nk) {        // wave-uniform
                                a[q][u4*4+0] = fmaf(-L0[q][m], uvv.x, a[q][u4*4+0]);
                                a[q][u4*4+1] = fmaf(-L0[q][m], uvv.y, a[q][u4*4+1]);
                                a[q][u4*4+2] = fmaf(-L0[q][m], uvv.z, a[q][u4*4+2]);
                                a[q][u4*4+3] = fmaf(-L0[q][m], uvv.w, a[q][u4*4+3]);
                            }
                        }
                    }
                }
            }
        }
        __syncthreads();                                  // B6
    }

    // ---- logdet = sum log|piv| (f64 accum), sign = parity of negatives ----
    if (tid < 64) {
        double ld = 0.0; int neg = 0;
        #pragma unroll
        for (int q = 0; q < 4; ++q) {
            float pv = s_piv[q*64 + tid];
            ld  += (double)logf(fabsf(pv));
            neg ^= (pv < 0.0f) ? 1 : 0;
        }
        #pragma unroll
        for (int off = 32; off; off >>= 1) {
            ld  += __shfl_xor(ld, off);
            neg ^= __shfl_xor(neg, off);
        }
        if (tid == 0) { out[0] = neg ? -1.0f : 1.0f; out[1] = (float)ld; }
    }
}

extern "C" void kernel_launch(void* const* d_in, const int* in_sizes, int n_in,
                              void* d_out, int out_size, void* d_ws, size_t ws_size,
                              hipStream_t stream)
{
    const float* x  = (const float*)d_in[0];
    const float* W0 = (const float*)d_in[1];
    const float* b0 = (const float*)d_in[2];
    const float* W1 = (const float*)d_in[3];
    const float* b1 = (const float*)d_in[4];
    const float* W2 = (const float*)d_in[5];
    const float* b2 = (const float*)d_in[6];
    float* out    = (float*)d_out;
    float* slater = (float*)d_ws;           // 256*256*4 = 256 KB scratch

    k_mlp_v5<<<512, 512, 0, stream>>>(x, W0, b0, W1, b1, W2, b2, slater);
    k_lu_blk<<<1, 512, 0, stream>>>(slater, out);
}